// Round 1
// baseline (1272.802 us; speedup 1.0000x reference)
//
#include <hip/hip_runtime.h>
#include <math.h>

#define B 512
#define T 500
#define ENC 1024
#define DEC 1024

// ---------------------------------------------------------------------------
// Kernel 1: sub[b,e] = sum_d dec[b,d] * W[e,d]   (C = A * W^T, both K-major)
// M=512 (b), N=1024 (e), K=1024 (d). BM=32, BN=64, BK=16, 256 threads,
// 2x4 microtile per thread. grid (16,16) = 256 blocks -> full CU coverage.
// ---------------------------------------------------------------------------
#define GM 32
#define GN 64
#define GK 16

__global__ __launch_bounds__(256) void gemm_sub(
    const float* __restrict__ A,   // [512,1024] decoderFeature
    const float* __restrict__ Wm,  // [1024,1024] W  (row e, col d)
    float* __restrict__ C)         // [512,1024] sub
{
    __shared__ float As[GK][GM + 2];  // [k][m], stride 34 floats (8B-aligned rows)
    __shared__ float Bs[GK][GN + 4];  // [k][n], stride 68 floats (16B-aligned rows)

    const int tid = threadIdx.x;
    const int bm0 = blockIdx.y * GM;   // over M=512, gridDim.y=16
    const int bn0 = blockIdx.x * GN;   // over N=1024, gridDim.x=16

    const int tx = tid & 15;           // col group: 4 cols each
    const int ty = tid >> 4;           // row group: 2 rows each

    float accr[2][4] = {{0.f,0.f,0.f,0.f},{0.f,0.f,0.f,0.f}};

    // loader indices
    const int arow = tid >> 3;          // 0..31
    const int acol = (tid & 7) * 2;     // 0..14
    const int brow = tid >> 2;          // 0..63
    const int bcol = (tid & 3) * 4;     // 0..12

    for (int k0 = 0; k0 < DEC; k0 += GK) {
        float2 a2 = *(const float2*)(A + (size_t)(bm0 + arow) * DEC + k0 + acol);
        As[acol][arow]     = a2.x;
        As[acol + 1][arow] = a2.y;
        float4 b4 = *(const float4*)(Wm + (size_t)(bn0 + brow) * DEC + k0 + bcol);
        Bs[bcol][brow]     = b4.x;
        Bs[bcol + 1][brow] = b4.y;
        Bs[bcol + 2][brow] = b4.z;
        Bs[bcol + 3][brow] = b4.w;
        __syncthreads();
#pragma unroll
        for (int k = 0; k < GK; k++) {
            float2 av = *(const float2*)&As[k][ty * 2];
            float4 bv = *(const float4*)&Bs[k][tx * 4];
            accr[0][0] = fmaf(av.x, bv.x, accr[0][0]);
            accr[0][1] = fmaf(av.x, bv.y, accr[0][1]);
            accr[0][2] = fmaf(av.x, bv.z, accr[0][2]);
            accr[0][3] = fmaf(av.x, bv.w, accr[0][3]);
            accr[1][0] = fmaf(av.y, bv.x, accr[1][0]);
            accr[1][1] = fmaf(av.y, bv.y, accr[1][1]);
            accr[1][2] = fmaf(av.y, bv.z, accr[1][2]);
            accr[1][3] = fmaf(av.y, bv.w, accr[1][3]);
        }
        __syncthreads();
    }

    float4 c0 = make_float4(accr[0][0], accr[0][1], accr[0][2], accr[0][3]);
    float4 c1 = make_float4(accr[1][0], accr[1][1], accr[1][2], accr[1][3]);
    *(float4*)(C + (size_t)(bm0 + ty * 2) * ENC + bn0 + tx * 4)     = c0;
    *(float4*)(C + (size_t)(bm0 + ty * 2 + 1) * ENC + bn0 + tx * 4) = c1;
}

// ---------------------------------------------------------------------------
// Kernel 2: fused attention with per-wave online softmax.
// One block (8 waves, 512 threads) per batch b. Wave w handles t = w, w+8, ...
// Lane l holds element slots e = c*256 + 4l + j (c=0..3, j=0..3) of:
//   sub row (registers), enc row (registers, prefetched), accumulator o.
// enc is read EXACTLY ONCE, and only for valid t < len.
// ---------------------------------------------------------------------------
#define NW 8
#define BLK (NW * 64)

__global__ __launch_bounds__(BLK, 4) void attn_fused(
    const float* __restrict__ sub,   // [B, ENC]
    const float* __restrict__ enc,   // [B, T, ENC]
    const int* __restrict__ lens,    // [B]
    float* __restrict__ out_attn,    // [B, T]
    float* __restrict__ out_sum)     // [B, ENC]
{
    __shared__ float lds_scores[T];
    __shared__ float lds_m[NW];
    __shared__ float lds_l[NW];
    __shared__ float lds_o[NW][ENC];

    const int b    = blockIdx.x;
    const int tid  = threadIdx.x;
    const int wave = tid >> 6;
    const int lane = tid & 63;
    const int len  = lens[b];

    const float* encb = enc + (size_t)b * T * ENC;
    const float* subb = sub + (size_t)b * ENC;

    float sub_r[16];
#pragma unroll
    for (int c = 0; c < 4; c++) {
        float4 s4 = *(const float4*)(subb + c * 256 + 4 * lane);
        sub_r[c * 4 + 0] = s4.x; sub_r[c * 4 + 1] = s4.y;
        sub_r[c * 4 + 2] = s4.z; sub_r[c * 4 + 3] = s4.w;
    }

    float acc[16];
#pragma unroll
    for (int i = 0; i < 16; i++) acc[i] = 0.f;
    float m = -INFINITY;
    float l = 0.f;

    int t = wave;
    float er[16];
    if (t < len) {
        const float* p = encb + (size_t)t * ENC + 4 * lane;
#pragma unroll
        for (int c = 0; c < 4; c++) {
            float4 v = *(const float4*)(p + c * 256);
            er[c * 4 + 0] = v.x; er[c * 4 + 1] = v.y;
            er[c * 4 + 2] = v.z; er[c * 4 + 3] = v.w;
        }
    }

    while (t < len) {
        const int tn = t + NW;
        float ern[16];
        if (tn < len) {
            const float* p = encb + (size_t)tn * ENC + 4 * lane;
#pragma unroll
            for (int c = 0; c < 4; c++) {
                float4 v = *(const float4*)(p + c * 256);
                ern[c * 4 + 0] = v.x; ern[c * 4 + 1] = v.y;
                ern[c * 4 + 2] = v.z; ern[c * 4 + 3] = v.w;
            }
        }

        // dot(sub_row, enc_row) across the wave
        float d = 0.f;
#pragma unroll
        for (int i = 0; i < 16; i++) d = fmaf(er[i], sub_r[i], d);
#pragma unroll
        for (int off = 32; off > 0; off >>= 1) d += __shfl_xor(d, off, 64);

        if (lane == 0) lds_scores[t] = d;

        // online softmax update (d is wave-uniform -> branch is uniform)
        if (d > m) {
            float alpha = __expf(m - d);  // first iter: exp(-inf) = 0
            l = l * alpha + 1.f;
#pragma unroll
            for (int i = 0; i < 16; i++) acc[i] = acc[i] * alpha + er[i];
            m = d;
        } else {
            float p = __expf(d - m);
            l += p;
#pragma unroll
            for (int i = 0; i < 16; i++) acc[i] = fmaf(p, er[i], acc[i]);
        }

        t = tn;
#pragma unroll
        for (int i = 0; i < 16; i++) er[i] = ern[i];
    }

    if (lane == 0) { lds_m[wave] = m; lds_l[wave] = l; }
#pragma unroll
    for (int c = 0; c < 4; c++) {
        float4 v = make_float4(acc[c * 4 + 0], acc[c * 4 + 1],
                               acc[c * 4 + 2], acc[c * 4 + 3]);
        *(float4*)&lds_o[wave][c * 256 + 4 * lane] = v;
    }
    __syncthreads();

    // combine 8 per-wave online-softmax states (every thread, redundantly)
    float mg = -INFINITY;
#pragma unroll
    for (int w = 0; w < NW; w++) mg = fmaxf(mg, lds_m[w]);
    float scale[NW];
    float lg = 0.f;
#pragma unroll
    for (int w = 0; w < NW; w++) {
        float mw = lds_m[w];
        float s  = (mw == -INFINITY) ? 0.f : __expf(mw - mg);
        scale[w] = s;
        lg = fmaf(lds_l[w], s, lg);
    }
    const float inv_l = 1.f / lg;   // len >= 1 guarantees lg > 0

    // sumResult: 2 elements per thread (1024 / 512)
    const int e0 = 2 * tid;
    float o0 = 0.f, o1 = 0.f;
#pragma unroll
    for (int w = 0; w < NW; w++) {
        o0 = fmaf(scale[w], lds_o[w][e0], o0);
        o1 = fmaf(scale[w], lds_o[w][e0 + 1], o1);
    }
    *(float2*)(out_sum + (size_t)b * ENC + e0) = make_float2(o0 * inv_l, o1 * inv_l);

    // attn probabilities (zeros for masked t)
    for (int tt = tid; tt < T; tt += BLK) {
        float v = 0.f;
        if (tt < len) v = __expf(lds_scores[tt] - mg) * inv_l;
        out_attn[(size_t)b * T + tt] = v;
    }
}

// ---------------------------------------------------------------------------
extern "C" void kernel_launch(void* const* d_in, const int* in_sizes, int n_in,
                              void* d_out, int out_size, void* d_ws, size_t ws_size,
                              hipStream_t stream) {
    const float* dec  = (const float*)d_in[0];   // [512,1024]
    const float* enc  = (const float*)d_in[1];   // [512,500,1024]
    const int*   lens = (const int*)d_in[2];     // [512]
    const float* Wm   = (const float*)d_in[3];   // [1024,1024]

    float* out       = (float*)d_out;
    float* out_attn  = out;                       // 512*500
    float* out_sum   = out + (size_t)B * T;       // 512*1024
    float* sub       = (float*)d_ws;              // 512*1024 floats = 2 MB scratch

    gemm_sub<<<dim3(16, 16), 256, 0, stream>>>(dec, Wm, sub);
    attn_fused<<<dim3(B), BLK, 0, stream>>>(sub, enc, lens, out_attn, out_sum);
}